// Round 7
// baseline (1581.968 us; speedup 1.0000x reference)
//
#include <hip/hip_runtime.h>
#include <math.h>

// Problem constants (match reference)
constexpr int NN = 100000;     // nodes
constexpr int DF = 512;        // input features
constexpr int C1 = 32;         // layer-1 width
constexpr int C2 = 16;         // layer-2 width
constexpr int NE = 3200000;    // edges
#define EPS_NORM 1e-7f

constexpr int BKT = 256;                     // rows per bucket
constexpr int NBKT = (NN + BKT - 1) / BKT;   // 391
constexpr int NCH = 256;                     // binning chunks
constexpr int CHUNK = NE / NCH;              // 12500 (exact)

// ---------------------------------------------------------------------------
// gemm1: XW1 = X @ W1, LDS-staged for coalescing.
// Block = 256 rows. K processed in 32-wide chunks: loads are 8 lanes/row
// (float4 each) -> every 128B segment fully used. LDS stride 33 floats ->
// conflict-free compute reads ((t+k)%32). W1 reads are wave-uniform (scalar).
// ---------------------------------------------------------------------------
__global__ __launch_bounds__(256) void gemm1_k(const float* __restrict__ X,
                                               const float* __restrict__ W1,
                                               float* __restrict__ XW1) {
    __shared__ float tile[256 * 33];
    int t = threadIdx.x;
    int rowbase = blockIdx.x * 256;
    float acc[C1];
#pragma unroll
    for (int j = 0; j < C1; ++j) acc[j] = 0.f;
    for (int c = 0; c < DF / 32; ++c) {
        __syncthreads();
#pragma unroll
        for (int i = 0; i < 8; ++i) {
            int li = i * 256 + t;
            int row = li >> 3;              // 8 lanes per row
            int o4 = (li & 7) * 4;
            int grow = rowbase + row;
            float4 v = make_float4(0.f, 0.f, 0.f, 0.f);
            if (grow < NN)
                v = *reinterpret_cast<const float4*>(X + (size_t)grow * DF + c * 32 + o4);
            tile[row * 33 + o4 + 0] = v.x;
            tile[row * 33 + o4 + 1] = v.y;
            tile[row * 33 + o4 + 2] = v.z;
            tile[row * 33 + o4 + 3] = v.w;
        }
        __syncthreads();
        const float* wb = W1 + c * 32 * C1;
#pragma unroll
        for (int k = 0; k < 32; ++k) {
            float xv = tile[t * 33 + k];
            const float* w = wb + k * C1;   // uniform
#pragma unroll
            for (int j = 0; j < C1; ++j) acc[j] = fmaf(xv, w[j], acc[j]);
        }
    }
    int grow = rowbase + t;
    if (grow < NN) {
        float4* o = reinterpret_cast<float4*>(XW1 + (size_t)grow * C1);
#pragma unroll
        for (int q = 0; q < C1 / 4; ++q)
            o[q] = make_float4(acc[4 * q], acc[4 * q + 1], acc[4 * q + 2], acc[4 * q + 3]);
    }
}

// ---------------------------------------------------------------------------
// Binning: edges -> 391 buckets of 256 rows. Per-chunk LDS histogram, scans,
// then fill with per-(chunk,bucket) contiguous writes (no line amplification).
// Payload: bpack = (col<<8)|rowlocal, bval = val.
// ---------------------------------------------------------------------------
__global__ __launch_bounds__(256) void bh_k(const int* __restrict__ rows,
                                            int* __restrict__ blkcnt) {
    __shared__ int lh[NBKT];
    int t = threadIdx.x, bi = blockIdx.x;
    for (int i = t; i < NBKT; i += 256) lh[i] = 0;
    __syncthreads();
    int base = bi * CHUNK;
    for (int i = t; i < CHUNK; i += 256)
        atomicAdd(&lh[rows[base + i] >> 8], 1);
    __syncthreads();
    for (int i = t; i < NBKT; i += 256) blkcnt[i * NCH + bi] = lh[i];
}

// exclusive scan over chunks within each bucket (one block per bucket)
__global__ __launch_bounds__(NCH) void bscan_k(int* __restrict__ blkcnt,
                                               int* __restrict__ bkttot) {
    __shared__ int sh[NCH];
    int t = threadIdx.x, b = blockIdx.x;
    int v = blkcnt[b * NCH + t];
    sh[t] = v;
    __syncthreads();
#pragma unroll
    for (int off = 1; off < NCH; off <<= 1) {
        int u = (t >= off) ? sh[t - off] : 0;
        __syncthreads();
        sh[t] += u;
        __syncthreads();
    }
    blkcnt[b * NCH + t] = sh[t] - v;   // exclusive
    if (t == NCH - 1) bkttot[b] = sh[t];
}

// exclusive scan over buckets (single block)
__global__ __launch_bounds__(512) void bscan2_k(const int* __restrict__ bkttot,
                                                int* __restrict__ bktstart) {
    __shared__ int sh[512];
    int t = threadIdx.x;
    sh[t] = (t < NBKT) ? bkttot[t] : 0;
    __syncthreads();
#pragma unroll
    for (int off = 1; off < 512; off <<= 1) {
        int u = (t >= off) ? sh[t - off] : 0;
        __syncthreads();
        sh[t] += u;
        __syncthreads();
    }
    if (t < NBKT) bktstart[t] = (t == 0) ? 0 : sh[t - 1];
    if (t == 0) bktstart[NBKT] = NE;
}

__global__ __launch_bounds__(256) void bfill_k(const int* __restrict__ rows,
                                               const int* __restrict__ cols,
                                               const float* __restrict__ vals,
                                               const int* __restrict__ blkcnt,
                                               const int* __restrict__ bktstart,
                                               unsigned int* __restrict__ bpack,
                                               float* __restrict__ bval) {
    __shared__ int cur[NBKT];
    int t = threadIdx.x, bi = blockIdx.x;
    for (int i = t; i < NBKT; i += 256) cur[i] = 0;
    __syncthreads();
    int base = bi * CHUNK;
    for (int i = t; i < CHUNK; i += 256) {
        int e = base + i;
        int r = rows[e];
        int bkt = r >> 8;
        int rank = atomicAdd(&cur[bkt], 1);
        int dst = bktstart[bkt] + blkcnt[bkt * NCH + bi] + rank;
        bpack[dst] = ((unsigned)cols[e] << 8) | (unsigned)(r & 255);
        bval[dst] = vals[e];
    }
}

// ---------------------------------------------------------------------------
// apply1: H1 = relu(Lap @ XW1) accumulated in LDS (ds_add_f32), then the
// tiny @W2 GEMM fused in the epilogue -> writes HW2 directly (H1 never hits
// global). One block per 256-row bucket; 32-lane subgroups own one edge.
// ---------------------------------------------------------------------------
__global__ __launch_bounds__(512) void apply1_k(const unsigned int* __restrict__ bpack,
                                                const float* __restrict__ bval,
                                                const int* __restrict__ bktstart,
                                                const float* __restrict__ XW1,
                                                const float* __restrict__ W2,
                                                float* __restrict__ HW2) {
    __shared__ float acc[256 * 33];
    int t = threadIdx.x, b = blockIdx.x;
    for (int i = t; i < 256 * 33; i += 512) acc[i] = 0.f;
    __syncthreads();
    int base = bktstart[b], end = bktstart[b + 1];
    int sub = t >> 5, j = t & 31;          // 16 subgroups x 32 lanes
    int i = base + sub;
    for (; i + 7 * 16 < end; i += 8 * 16) {
        unsigned p[8]; float v[8];
#pragma unroll
        for (int u = 0; u < 8; ++u) { p[u] = bpack[i + u * 16]; v[u] = bval[i + u * 16]; }
        float x[8];
#pragma unroll
        for (int u = 0; u < 8; ++u) x[u] = XW1[(size_t)(p[u] >> 8) * C1 + j];
#pragma unroll
        for (int u = 0; u < 8; ++u) atomicAdd(&acc[(p[u] & 255u) * 33 + j], v[u] * x[u]);
    }
    for (; i < end; i += 16) {
        unsigned p = bpack[i]; float v = bval[i];
        float x = XW1[(size_t)(p >> 8) * C1 + j];
        atomicAdd(&acc[(p & 255u) * 33 + j], v * x);
    }
    __syncthreads();
    // epilogue: relu + @W2 (thread t = row t of the bucket)
    int grow = b * 256 + t;
    if (t < 256 && grow < NN) {
        float h[C1];
#pragma unroll
        for (int k = 0; k < C1; ++k) h[k] = fmaxf(acc[t * 33 + k], 0.f);
        float o[C2];
#pragma unroll
        for (int q = 0; q < C2; ++q) o[q] = 0.f;
#pragma unroll
        for (int k = 0; k < C1; ++k) {
            const float* w = W2 + k * C2;   // uniform
#pragma unroll
            for (int q = 0; q < C2; ++q) o[q] = fmaf(h[k], w[q], o[q]);
        }
        float4* op = reinterpret_cast<float4*>(HW2 + (size_t)grow * C2);
#pragma unroll
        for (int q = 0; q < C2 / 4; ++q)
            op[q] = make_float4(o[4 * q], o[4 * q + 1], o[4 * q + 2], o[4 * q + 3]);
    }
}

// ---------------------------------------------------------------------------
// apply2: out = Lap @ HW2 in LDS, fused row-L2 normalization on write.
// 32 subgroups x 16 lanes.
// ---------------------------------------------------------------------------
__global__ __launch_bounds__(512) void apply2_k(const unsigned int* __restrict__ bpack,
                                                const float* __restrict__ bval,
                                                const int* __restrict__ bktstart,
                                                const float* __restrict__ HW2,
                                                float* __restrict__ out) {
    __shared__ float acc[256 * 17];
    int t = threadIdx.x, b = blockIdx.x;
    for (int i = t; i < 256 * 17; i += 512) acc[i] = 0.f;
    __syncthreads();
    int base = bktstart[b], end = bktstart[b + 1];
    int sub = t >> 4, j = t & 15;          // 32 subgroups x 16 lanes
    int i = base + sub;
    for (; i + 7 * 32 < end; i += 8 * 32) {
        unsigned p[8]; float v[8];
#pragma unroll
        for (int u = 0; u < 8; ++u) { p[u] = bpack[i + u * 32]; v[u] = bval[i + u * 32]; }
        float x[8];
#pragma unroll
        for (int u = 0; u < 8; ++u) x[u] = HW2[(size_t)(p[u] >> 8) * C2 + j];
#pragma unroll
        for (int u = 0; u < 8; ++u) atomicAdd(&acc[(p[u] & 255u) * 17 + j], v[u] * x[u]);
    }
    for (; i < end; i += 32) {
        unsigned p = bpack[i]; float v = bval[i];
        float x = HW2[(size_t)(p >> 8) * C2 + j];
        atomicAdd(&acc[(p & 255u) * 17 + j], v * x);
    }
    __syncthreads();
    // epilogue: row-L2 norm, 16 consecutive lanes per row -> coalesced writes
    for (int r = (t >> 4); r < 256; r += 32) {
        int grow = b * 256 + r;
        if (grow >= NN) break;
        float val = acc[r * 17 + j];
        float s = val * val;
#pragma unroll
        for (int m = 1; m < 16; m <<= 1) s += __shfl_xor(s, m);
        out[(size_t)grow * C2 + j] = val / fmaxf(sqrtf(s), EPS_NORM);
    }
}

// ---------------------------------------------------------------------------
// Fallback path (atomic scatter, round-4 style) if ws_size is too small.
// ---------------------------------------------------------------------------
__global__ __launch_bounds__(64) void gemm2_k(const float* __restrict__ H1,
                                              const float* __restrict__ W2,
                                              float* __restrict__ HW2) {
    int row = blockIdx.x * 64 + threadIdx.x;
    if (row >= NN) return;
    float h[C1];
    const float4* hr = reinterpret_cast<const float4*>(H1 + (size_t)row * C1);
#pragma unroll
    for (int q = 0; q < C1 / 4; ++q) {
        float4 v = hr[q];
        h[4 * q + 0] = fmaxf(v.x, 0.f);
        h[4 * q + 1] = fmaxf(v.y, 0.f);
        h[4 * q + 2] = fmaxf(v.z, 0.f);
        h[4 * q + 3] = fmaxf(v.w, 0.f);
    }
    float acc[C2];
#pragma unroll
    for (int j = 0; j < C2; ++j) acc[j] = 0.f;
#pragma unroll
    for (int k = 0; k < C1; ++k) {
        const float* w = W2 + k * C2;
#pragma unroll
        for (int j = 0; j < C2; ++j) acc[j] = fmaf(h[k], w[j], acc[j]);
    }
    float4* o = reinterpret_cast<float4*>(HW2 + (size_t)row * C2);
#pragma unroll
    for (int q = 0; q < C2 / 4; ++q)
        o[q] = make_float4(acc[4 * q], acc[4 * q + 1], acc[4 * q + 2], acc[4 * q + 3]);
}

template <int F>
__global__ __launch_bounds__(256) void spmm_k(const int* __restrict__ rows,
                                              const int* __restrict__ cols,
                                              const float* __restrict__ vals,
                                              const float* __restrict__ Hin,
                                              float* __restrict__ Hout) {
    constexpr int SH = (F == 32) ? 5 : 4;
    constexpr int MSK = F - 1;
    long long total = (long long)NE << SH;
    long long stride = (long long)gridDim.x * 256;
    for (long long idx = (long long)blockIdx.x * 256 + threadIdx.x; idx < total;
         idx += stride) {
        int e = (int)(idx >> SH);
        int j = (int)(idx & MSK);
        float contrib = vals[e] * Hin[(size_t)cols[e] * F + j];
        unsafeAtomicAdd(&Hout[(size_t)rows[e] * F + j], contrib);
    }
}

__global__ __launch_bounds__(256) void norm_k(float* __restrict__ H) {
    int t = blockIdx.x * 256 + threadIdx.x;
    if (t >= NN * C2) return;
    float v = H[t];
    float s = v * v;
#pragma unroll
    for (int m = 1; m < C2; m <<= 1) s += __shfl_xor(s, m, C2);
    H[t] = v / fmaxf(sqrtf(s), EPS_NORM);
}

extern "C" void kernel_launch(void* const* d_in, const int* in_sizes, int n_in,
                              void* d_out, int out_size, void* d_ws, size_t ws_size,
                              hipStream_t stream) {
    const float* X = (const float*)d_in[0];
    const float* W1 = (const float*)d_in[1];
    const float* W2 = (const float*)d_in[2];
    const int* lap_rows = (const int*)d_in[3];
    const int* lap_cols = (const int*)d_in[4];
    const float* vals = (const float*)d_in[5];
    float* out = (float*)d_out;

    // workspace layout (main path): 45.2 MB
    float* XW1 = (float*)d_ws;                            // NN*C1
    float* HW2 = XW1 + (size_t)NN * C1;                   // NN*C2
    unsigned int* bpack = (unsigned int*)(HW2 + (size_t)NN * C2);  // NE
    float* bval = (float*)(bpack + NE);                   // NE
    int* blkcnt = (int*)(bval + NE);                      // NBKT*NCH
    int* bkttot = blkcnt + NBKT * NCH;                    // NBKT
    int* bktstart = bkttot + NBKT;                        // NBKT+1
    size_t need = (size_t)((char*)(bktstart + NBKT + 1) - (char*)d_ws);

    if (ws_size >= need) {
        // binning (int LDS atomics only; contiguous payload writes)
        bh_k<<<NCH, 256, 0, stream>>>(lap_rows, blkcnt);
        bscan_k<<<NBKT, NCH, 0, stream>>>(blkcnt, bkttot);
        bscan2_k<<<1, 512, 0, stream>>>(bkttot, bktstart);
        bfill_k<<<NCH, 256, 0, stream>>>(lap_rows, lap_cols, vals, blkcnt,
                                         bktstart, bpack, bval);
        // pipeline (no global f32 atomics anywhere)
        gemm1_k<<<(NN + 255) / 256, 256, 0, stream>>>(X, W1, XW1);
        apply1_k<<<NBKT, 512, 0, stream>>>(bpack, bval, bktstart, XW1, W2, HW2);
        apply2_k<<<NBKT, 512, 0, stream>>>(bpack, bval, bktstart, HW2, out);
    } else {
        // fallback: atomic-scatter path (32 MB of ws)
        float* H1 = (float*)bpack;   // reuse region
        hipMemsetAsync(H1, 0, (size_t)NN * C1 * sizeof(float), stream);
        hipMemsetAsync(out, 0, (size_t)NN * C2 * sizeof(float), stream);
        gemm1_k<<<(NN + 255) / 256, 256, 0, stream>>>(X, W1, XW1);
        spmm_k<C1><<<16384, 256, 0, stream>>>(lap_rows, lap_cols, vals, XW1, H1);
        gemm2_k<<<(NN + 63) / 64, 64, 0, stream>>>(H1, W2, HW2);
        spmm_k<C2><<<8192, 256, 0, stream>>>(lap_rows, lap_cols, vals, HW2, out);
        norm_k<<<((NN * C2) + 255) / 256, 256, 0, stream>>>(out);
    }
}

// Round 9
// 1365.472 us; speedup vs baseline: 1.1586x; 1.1586x over previous
//
#include <hip/hip_runtime.h>
#include <math.h>

// Problem constants (match reference)
constexpr int NN = 100000;     // nodes
constexpr int DF = 512;        // input features
constexpr int C1 = 32;         // layer-1 width
constexpr int C2 = 16;         // layer-2 width
constexpr int NE = 3200000;    // edges
#define EPS_NORM 1e-7f

constexpr int BKT = 64;                      // rows per bucket
constexpr int NBKT = (NN + BKT - 1) / BKT;   // 1563
constexpr int NCH = 256;                     // binning chunks
constexpr int CHUNK = NE / NCH;              // 12500 (exact)

// ---------------------------------------------------------------------------
// gemm1: XW1 = X @ W1. Block = 4 waves x 64 rows; wave wc streams K-quarter
// [wc*128, wc*128+128). W1 addresses wave-uniform -> scalar s_loads; X loads
// are per-lane contiguous 16B streams (every 64B line fully consumed).
// Partials combined once through LDS. 1563 blocks -> ~6 waves/SIMD.
// ---------------------------------------------------------------------------
__global__ __launch_bounds__(256) void gemm1_k(const float* __restrict__ X,
                                               const float* __restrict__ W1,
                                               float* __restrict__ XW1) {
    __shared__ float part[64][36];
    int t = threadIdx.x;
    int l = t & 63;
    int wc = __builtin_amdgcn_readfirstlane(t >> 6);
    int grow = blockIdx.x * 64 + l;
    bool valid = grow < NN;
    float acc[C1];
#pragma unroll
    for (int j = 0; j < C1; ++j) acc[j] = 0.f;
    if (valid) {
        const float4* xp = reinterpret_cast<const float4*>(X + (size_t)grow * DF + wc * 128);
        const float* wb = W1 + (size_t)wc * 128 * C1;
#pragma unroll 1
        for (int kk = 0; kk < 32; kk += 4) {
            float4 xv[4];
#pragma unroll
            for (int u = 0; u < 4; ++u) xv[u] = xp[kk + u];
#pragma unroll
            for (int u = 0; u < 4; ++u) {
                const float* w = wb + (size_t)(kk + u) * 4 * C1;   // wave-uniform
#pragma unroll
                for (int j = 0; j < C1; ++j) acc[j] = fmaf(xv[u].x, w[j], acc[j]);
#pragma unroll
                for (int j = 0; j < C1; ++j) acc[j] = fmaf(xv[u].y, w[C1 + j], acc[j]);
#pragma unroll
                for (int j = 0; j < C1; ++j) acc[j] = fmaf(xv[u].z, w[2 * C1 + j], acc[j]);
#pragma unroll
                for (int j = 0; j < C1; ++j) acc[j] = fmaf(xv[u].w, w[3 * C1 + j], acc[j]);
            }
        }
    }
    // combine the 4 wave-partials
    if (wc == 0) {
#pragma unroll
        for (int j = 0; j < C1; ++j) part[l][j] = acc[j];
    }
    __syncthreads();
    if (wc == 1) {
#pragma unroll
        for (int j = 0; j < C1; ++j) part[l][j] += acc[j];
    }
    __syncthreads();
    if (wc == 2) {
#pragma unroll
        for (int j = 0; j < C1; ++j) part[l][j] += acc[j];
    }
    __syncthreads();
    if (wc == 3 && valid) {
        float4* o = reinterpret_cast<float4*>(XW1 + (size_t)grow * C1);
#pragma unroll
        for (int q = 0; q < C1 / 4; ++q) {
            float4 r;
            r.x = part[l][4 * q + 0] + acc[4 * q + 0];
            r.y = part[l][4 * q + 1] + acc[4 * q + 1];
            r.z = part[l][4 * q + 2] + acc[4 * q + 2];
            r.w = part[l][4 * q + 3] + acc[4 * q + 3];
            o[q] = r;
        }
    }
}

// ---------------------------------------------------------------------------
// Binning: edges -> 1563 buckets of 64 rows. Per-chunk LDS histogram, scans,
// then fill. Payload: edata = { (col<<6)|rowlocal , bits(val) } (one uint2).
// Per-(chunk,bucket) runs ~8 edges x 8 B = full 64B lines.
// ---------------------------------------------------------------------------
__global__ __launch_bounds__(256) void bh_k(const int* __restrict__ rows,
                                            int* __restrict__ blkcnt) {
    __shared__ int lh[NBKT];
    int t = threadIdx.x, bi = blockIdx.x;
    for (int i = t; i < NBKT; i += 256) lh[i] = 0;
    __syncthreads();
    int base = bi * CHUNK;
    for (int i = t; i < CHUNK; i += 256)
        atomicAdd(&lh[rows[base + i] >> 6], 1);
    __syncthreads();
    for (int i = t; i < NBKT; i += 256) blkcnt[(size_t)i * NCH + bi] = lh[i];
}

// exclusive scan over chunks within each bucket (one block per bucket)
__global__ __launch_bounds__(NCH) void bscan_k(int* __restrict__ blkcnt,
                                               int* __restrict__ bkttot) {
    __shared__ int sh[NCH];
    int t = threadIdx.x, b = blockIdx.x;
    int v = blkcnt[(size_t)b * NCH + t];
    sh[t] = v;
    __syncthreads();
#pragma unroll
    for (int off = 1; off < NCH; off <<= 1) {
        int u = (t >= off) ? sh[t - off] : 0;
        __syncthreads();
        sh[t] += u;
        __syncthreads();
    }
    blkcnt[(size_t)b * NCH + t] = sh[t] - v;   // exclusive
    if (t == NCH - 1) bkttot[b] = sh[t];
}

// exclusive scan over the 1563 buckets (single block, 2 elems/thread)
__global__ __launch_bounds__(1024) void bscan2_k(const int* __restrict__ bkttot,
                                                 int* __restrict__ bktstart) {
    __shared__ int sh[1024];
    int t = threadIdx.x;
    int i0 = 2 * t, i1 = 2 * t + 1;
    int a = (i0 < NBKT) ? bkttot[i0] : 0;
    int b = (i1 < NBKT) ? bkttot[i1] : 0;
    int s = a + b;
    sh[t] = s;
    __syncthreads();
#pragma unroll
    for (int off = 1; off < 1024; off <<= 1) {
        int u = (t >= off) ? sh[t - off] : 0;
        __syncthreads();
        sh[t] += u;
        __syncthreads();
    }
    int excl = sh[t] - s;
    if (i0 < NBKT) bktstart[i0] = excl;
    if (i1 < NBKT) bktstart[i1] = excl + a;
    if (t == 0) bktstart[NBKT] = NE;
}

__global__ __launch_bounds__(256) void bfill_k(const int* __restrict__ rows,
                                               const int* __restrict__ cols,
                                               const float* __restrict__ vals,
                                               const int* __restrict__ blkcnt,
                                               const int* __restrict__ bktstart,
                                               uint2* __restrict__ edata) {
    __shared__ int cur[NBKT];
    int t = threadIdx.x, bi = blockIdx.x;
    for (int i = t; i < NBKT; i += 256) cur[i] = 0;
    __syncthreads();
    int base = bi * CHUNK;
    for (int i = t; i < CHUNK; i += 256) {
        int e = base + i;
        int r = rows[e];
        int bkt = r >> 6;
        int rank = atomicAdd(&cur[bkt], 1);
        int dst = bktstart[bkt] + blkcnt[(size_t)bkt * NCH + bi] + rank;
        edata[dst] = make_uint2(((unsigned)cols[e] << 6) | (unsigned)(r & 63),
                                __float_as_uint(vals[e]));
    }
}

// ---------------------------------------------------------------------------
// apply1: H1 = relu(Lap @ XW1) accumulated into an LDS tile (ds_add_f32),
// with the tiny @W2 GEMM fused in the epilogue (H1 never touches global).
// One block per 64-row bucket; 16 subgroups of 32 lanes, 8-deep pipelined.
// ---------------------------------------------------------------------------
__global__ __launch_bounds__(512) void apply1_k(const uint2* __restrict__ edata,
                                                const int* __restrict__ bktstart,
                                                const float* __restrict__ XW1,
                                                const float* __restrict__ W2,
                                                float* __restrict__ HW2) {
    __shared__ float acc[64 * 33];
    int t = threadIdx.x, b = blockIdx.x;
    for (int i = t; i < 64 * 33; i += 512) acc[i] = 0.f;
    __syncthreads();
    int base = bktstart[b], end = bktstart[b + 1];
    int sub = t >> 5, j = t & 31;          // 16 subgroups x 32 lanes
    int i = base + sub;
    for (; i + 7 * 16 < end; i += 8 * 16) {
        uint2 ed[8];
#pragma unroll
        for (int u = 0; u < 8; ++u) ed[u] = edata[i + u * 16];
        float x[8];
#pragma unroll
        for (int u = 0; u < 8; ++u) x[u] = XW1[(size_t)(ed[u].x >> 6) * C1 + j];
#pragma unroll
        for (int u = 0; u < 8; ++u)
            atomicAdd(&acc[(ed[u].x & 63u) * 33 + j], __uint_as_float(ed[u].y) * x[u]);
    }
    for (; i < end; i += 16) {
        uint2 ed = edata[i];
        float x = XW1[(size_t)(ed.x >> 6) * C1 + j];
        atomicAdd(&acc[(ed.x & 63u) * 33 + j], __uint_as_float(ed.y) * x);
    }
    __syncthreads();
    // epilogue: relu + @W2. thread t: row r = t>>3, cols {2s, 2s+1}, s = t&7
    int r = t >> 3, s = t & 7;
    int grow = b * 64 + r;
    if (grow < NN) {
        float o0 = 0.f, o1 = 0.f;
#pragma unroll
        for (int k = 0; k < C1; ++k) {
            float h = fmaxf(acc[r * 33 + k], 0.f);
            o0 = fmaf(h, W2[k * C2 + 2 * s], o0);
            o1 = fmaf(h, W2[k * C2 + 2 * s + 1], o1);
        }
        float2* op = reinterpret_cast<float2*>(HW2 + (size_t)grow * C2 + 2 * s);
        *op = make_float2(o0, o1);
    }
}

// ---------------------------------------------------------------------------
// apply2: out = Lap @ HW2 into LDS, fused row-L2 normalization on write.
// 32 subgroups x 16 lanes per block.
// ---------------------------------------------------------------------------
__global__ __launch_bounds__(512) void apply2_k(const uint2* __restrict__ edata,
                                                const int* __restrict__ bktstart,
                                                const float* __restrict__ HW2,
                                                float* __restrict__ out) {
    __shared__ float acc[64 * 17];
    int t = threadIdx.x, b = blockIdx.x;
    for (int i = t; i < 64 * 17; i += 512) acc[i] = 0.f;
    __syncthreads();
    int base = bktstart[b], end = bktstart[b + 1];
    int sub = t >> 4, j = t & 15;          // 32 subgroups x 16 lanes
    int i = base + sub;
    for (; i + 7 * 32 < end; i += 8 * 32) {
        uint2 ed[8];
#pragma unroll
        for (int u = 0; u < 8; ++u) ed[u] = edata[i + u * 32];
        float x[8];
#pragma unroll
        for (int u = 0; u < 8; ++u) x[u] = HW2[(size_t)(ed[u].x >> 6) * C2 + j];
#pragma unroll
        for (int u = 0; u < 8; ++u)
            atomicAdd(&acc[(ed[u].x & 63u) * 17 + j], __uint_as_float(ed[u].y) * x[u]);
    }
    for (; i < end; i += 32) {
        uint2 ed = edata[i];
        float x = HW2[(size_t)(ed.x >> 6) * C2 + j];
        atomicAdd(&acc[(ed.x & 63u) * 17 + j], __uint_as_float(ed.y) * x);
    }
    __syncthreads();
    // epilogue: row-L2 norm; 16 consecutive lanes per row -> coalesced writes
    for (int r = (t >> 4); r < 64; r += 32) {
        int grow = b * 64 + r;
        if (grow >= NN) break;
        float val = acc[r * 17 + j];
        float s = val * val;
#pragma unroll
        for (int m = 1; m < 16; m <<= 1) s += __shfl_xor(s, m);
        out[(size_t)grow * C2 + j] = val / fmaxf(sqrtf(s), EPS_NORM);
    }
}

// ---------------------------------------------------------------------------
// Fallback path (atomic scatter, round-4 style) if ws_size is too small.
// ---------------------------------------------------------------------------
__global__ __launch_bounds__(64) void gemm2_k(const float* __restrict__ H1,
                                              const float* __restrict__ W2,
                                              float* __restrict__ HW2) {
    int row = blockIdx.x * 64 + threadIdx.x;
    if (row >= NN) return;
    float h[C1];
    const float4* hr = reinterpret_cast<const float4*>(H1 + (size_t)row * C1);
#pragma unroll
    for (int q = 0; q < C1 / 4; ++q) {
        float4 v = hr[q];
        h[4 * q + 0] = fmaxf(v.x, 0.f);
        h[4 * q + 1] = fmaxf(v.y, 0.f);
        h[4 * q + 2] = fmaxf(v.z, 0.f);
        h[4 * q + 3] = fmaxf(v.w, 0.f);
    }
    float acc[C2];
#pragma unroll
    for (int j = 0; j < C2; ++j) acc[j] = 0.f;
#pragma unroll
    for (int k = 0; k < C1; ++k) {
        const float* w = W2 + k * C2;
#pragma unroll
        for (int j = 0; j < C2; ++j) acc[j] = fmaf(h[k], w[j], acc[j]);
    }
    float4* o = reinterpret_cast<float4*>(HW2 + (size_t)row * C2);
#pragma unroll
    for (int q = 0; q < C2 / 4; ++q)
        o[q] = make_float4(acc[4 * q], acc[4 * q + 1], acc[4 * q + 2], acc[4 * q + 3]);
}

template <int F>
__global__ __launch_bounds__(256) void spmm_k(const int* __restrict__ rows,
                                              const int* __restrict__ cols,
                                              const float* __restrict__ vals,
                                              const float* __restrict__ Hin,
                                              float* __restrict__ Hout) {
    constexpr int SH = (F == 32) ? 5 : 4;
    constexpr int MSK = F - 1;
    long long total = (long long)NE << SH;
    long long stride = (long long)gridDim.x * 256;
    for (long long idx = (long long)blockIdx.x * 256 + threadIdx.x; idx < total;
         idx += stride) {
        int e = (int)(idx >> SH);
        int j = (int)(idx & MSK);
        float contrib = vals[e] * Hin[(size_t)cols[e] * F + j];
        unsafeAtomicAdd(&Hout[(size_t)rows[e] * F + j], contrib);
    }
}

__global__ __launch_bounds__(256) void norm_k(float* __restrict__ H) {
    int t = blockIdx.x * 256 + threadIdx.x;
    if (t >= NN * C2) return;
    float v = H[t];
    float s = v * v;
#pragma unroll
    for (int m = 1; m < C2; m <<= 1) s += __shfl_xor(s, m, C2);
    H[t] = v / fmaxf(sqrtf(s), EPS_NORM);
}

extern "C" void kernel_launch(void* const* d_in, const int* in_sizes, int n_in,
                              void* d_out, int out_size, void* d_ws, size_t ws_size,
                              hipStream_t stream) {
    const float* X = (const float*)d_in[0];
    const float* W1 = (const float*)d_in[1];
    const float* W2 = (const float*)d_in[2];
    const int* lap_rows = (const int*)d_in[3];
    const int* lap_cols = (const int*)d_in[4];
    const float* vals = (const float*)d_in[5];
    float* out = (float*)d_out;

    // workspace layout (main path): ~46.5 MB
    float* XW1 = (float*)d_ws;                            // NN*C1
    float* HW2 = XW1 + (size_t)NN * C1;                   // NN*C2
    uint2* edata = (uint2*)(HW2 + (size_t)NN * C2);       // NE uint2
    int* blkcnt = (int*)(edata + NE);                     // NBKT*NCH
    int* bkttot = blkcnt + (size_t)NBKT * NCH;            // NBKT
    int* bktstart = bkttot + NBKT;                        // NBKT+1
    size_t need = (size_t)((char*)(bktstart + NBKT + 1) - (char*)d_ws);

    if (ws_size >= need) {
        // binning (int LDS atomics only; line-granular payload writes)
        bh_k<<<NCH, 256, 0, stream>>>(lap_rows, blkcnt);
        bscan_k<<<NBKT, NCH, 0, stream>>>(blkcnt, bkttot);
        bscan2_k<<<1, 1024, 0, stream>>>(bkttot, bktstart);
        bfill_k<<<NCH, 256, 0, stream>>>(lap_rows, lap_cols, vals, blkcnt,
                                         bktstart, edata);
        // pipeline (no global f32 atomics anywhere)
        gemm1_k<<<NBKT, 256, 0, stream>>>(X, W1, XW1);
        apply1_k<<<NBKT, 512, 0, stream>>>(edata, bktstart, XW1, W2, HW2);
        apply2_k<<<NBKT, 512, 0, stream>>>(edata, bktstart, HW2, out);
    } else {
        // fallback: atomic-scatter path (32 MB of ws)
        float* H1 = (float*)edata;   // reuse region
        hipMemsetAsync(H1, 0, (size_t)NN * C1 * sizeof(float), stream);
        hipMemsetAsync(out, 0, (size_t)NN * C2 * sizeof(float), stream);
        gemm1_k<<<NBKT, 256, 0, stream>>>(X, W1, XW1);
        spmm_k<C1><<<16384, 256, 0, stream>>>(lap_rows, lap_cols, vals, XW1, H1);
        gemm2_k<<<(NN + 63) / 64, 64, 0, stream>>>(H1, W2, HW2);
        spmm_k<C2><<<8192, 256, 0, stream>>>(lap_rows, lap_cols, vals, HW2, out);
        norm_k<<<((NN * C2) + 255) / 256, 256, 0, stream>>>(out);
    }
}

// Round 14
// 1358.424 us; speedup vs baseline: 1.1646x; 1.0052x over previous
//
#include <hip/hip_runtime.h>
#include <math.h>

// Problem constants (match reference)
constexpr int NN = 100000;     // nodes
constexpr int DF = 512;        // input features
constexpr int C1 = 32;         // layer-1 width
constexpr int C2 = 16;         // layer-2 width
constexpr int NE = 3200000;    // edges
#define EPS_NORM 1e-7f

constexpr int BKT = 64;                      // rows per bucket
constexpr int NBKT = (NN + BKT - 1) / BKT;   // 1563
constexpr int NCH = 256;                     // binning chunks
constexpr int CHUNK = NE / NCH;              // 12500 (exact)

// ---------------------------------------------------------------------------
// gemm1: XW1 = X @ W1. Block = 4 waves x 64 rows; wave wc streams K-quarter.
// launch_bounds(256,4): VGPR cap 128 so the 8-deep float4 preload stays in
// registers (needs ~80). W1 wave-uniform -> scalar s_loads.
// ---------------------------------------------------------------------------
__global__ __launch_bounds__(256, 4) void gemm1_k(const float* __restrict__ X,
                                                  const float* __restrict__ W1,
                                                  float* __restrict__ XW1) {
    __shared__ float part[64][36];
    int t = threadIdx.x;
    int l = t & 63;
    int wc = __builtin_amdgcn_readfirstlane(t >> 6);
    int grow = blockIdx.x * 64 + l;
    bool valid = grow < NN;
    float acc[C1];
#pragma unroll
    for (int j = 0; j < C1; ++j) acc[j] = 0.f;
    if (valid) {
        const float4* xp = reinterpret_cast<const float4*>(X + (size_t)grow * DF + wc * 128);
        const float* wb = W1 + (size_t)wc * 128 * C1;
#pragma unroll 1
        for (int kk = 0; kk < 32; kk += 8) {
            float4 xv[8];
#pragma unroll
            for (int u = 0; u < 8; ++u) xv[u] = xp[kk + u];
#pragma unroll
            for (int u = 0; u < 8; ++u) {
                const float* w = wb + (size_t)(kk + u) * 4 * C1;   // wave-uniform
#pragma unroll
                for (int j = 0; j < C1; ++j) acc[j] = fmaf(xv[u].x, w[j], acc[j]);
#pragma unroll
                for (int j = 0; j < C1; ++j) acc[j] = fmaf(xv[u].y, w[C1 + j], acc[j]);
#pragma unroll
                for (int j = 0; j < C1; ++j) acc[j] = fmaf(xv[u].z, w[2 * C1 + j], acc[j]);
#pragma unroll
                for (int j = 0; j < C1; ++j) acc[j] = fmaf(xv[u].w, w[3 * C1 + j], acc[j]);
            }
        }
    }
    if (wc == 0) {
#pragma unroll
        for (int j = 0; j < C1; ++j) part[l][j] = acc[j];
    }
    __syncthreads();
    if (wc == 1) {
#pragma unroll
        for (int j = 0; j < C1; ++j) part[l][j] += acc[j];
    }
    __syncthreads();
    if (wc == 2) {
#pragma unroll
        for (int j = 0; j < C1; ++j) part[l][j] += acc[j];
    }
    __syncthreads();
    if (wc == 3 && valid) {
        float4* o = reinterpret_cast<float4*>(XW1 + (size_t)grow * C1);
#pragma unroll
        for (int q = 0; q < C1 / 4; ++q) {
            float4 r;
            r.x = part[l][4 * q + 0] + acc[4 * q + 0];
            r.y = part[l][4 * q + 1] + acc[4 * q + 1];
            r.z = part[l][4 * q + 2] + acc[4 * q + 2];
            r.w = part[l][4 * q + 3] + acc[4 * q + 3];
            o[q] = r;
        }
    }
}

// ---------------------------------------------------------------------------
// Binning: edges -> 1563 buckets of 64 rows. 512 threads (these run at
// exactly 1 block/CU so thread count is the only TLP lever).
// ---------------------------------------------------------------------------
__global__ __launch_bounds__(512) void bh_k(const int* __restrict__ rows,
                                            int* __restrict__ blkcnt) {
    __shared__ int lh[NBKT];
    int t = threadIdx.x, bi = blockIdx.x;
    for (int i = t; i < NBKT; i += 512) lh[i] = 0;
    __syncthreads();
    int base = bi * CHUNK;
    for (int i = t; i < CHUNK; i += 512)
        atomicAdd(&lh[rows[base + i] >> 6], 1);
    __syncthreads();
    for (int i = t; i < NBKT; i += 512) blkcnt[(size_t)i * NCH + bi] = lh[i];
}

__global__ __launch_bounds__(NCH) void bscan_k(int* __restrict__ blkcnt,
                                               int* __restrict__ bkttot) {
    __shared__ int sh[NCH];
    int t = threadIdx.x, b = blockIdx.x;
    int v = blkcnt[(size_t)b * NCH + t];
    sh[t] = v;
    __syncthreads();
#pragma unroll
    for (int off = 1; off < NCH; off <<= 1) {
        int u = (t >= off) ? sh[t - off] : 0;
        __syncthreads();
        sh[t] += u;
        __syncthreads();
    }
    blkcnt[(size_t)b * NCH + t] = sh[t] - v;   // exclusive
    if (t == NCH - 1) bkttot[b] = sh[t];
}

__global__ __launch_bounds__(1024) void bscan2_k(const int* __restrict__ bkttot,
                                                 int* __restrict__ bktstart) {
    __shared__ int sh[1024];
    int t = threadIdx.x;
    int i0 = 2 * t, i1 = 2 * t + 1;
    int a = (i0 < NBKT) ? bkttot[i0] : 0;
    int b = (i1 < NBKT) ? bkttot[i1] : 0;
    int s = a + b;
    sh[t] = s;
    __syncthreads();
#pragma unroll
    for (int off = 1; off < 1024; off <<= 1) {
        int u = (t >= off) ? sh[t - off] : 0;
        __syncthreads();
        sh[t] += u;
        __syncthreads();
    }
    int excl = sh[t] - s;
    if (i0 < NBKT) bktstart[i0] = excl;
    if (i1 < NBKT) bktstart[i1] = excl + a;
    if (t == 0) bktstart[NBKT] = NE;
}

__global__ __launch_bounds__(512) void bfill_k(const int* __restrict__ rows,
                                               const int* __restrict__ cols,
                                               const float* __restrict__ vals,
                                               const int* __restrict__ blkcnt,
                                               const int* __restrict__ bktstart,
                                               uint2* __restrict__ edata) {
    __shared__ int cur[NBKT];
    int t = threadIdx.x, bi = blockIdx.x;
    for (int i = t; i < NBKT; i += 512) cur[i] = 0;
    __syncthreads();
    int base = bi * CHUNK;
    for (int i = t; i < CHUNK; i += 512) {
        int e = base + i;
        int r = rows[e];
        int bkt = r >> 6;
        int rank = atomicAdd(&cur[bkt], 1);
        int dst = bktstart[bkt] + blkcnt[(size_t)bkt * NCH + bi] + rank;
        edata[dst] = make_uint2(((unsigned)cols[e] << 6) | (unsigned)(r & 63),
                                __float_as_uint(vals[e]));
    }
}

// ---------------------------------------------------------------------------
// apply1: H1 = relu(Lap @ XW1) in LDS (ds_add_f32), fused @W2 epilogue.
// 256 threads = 8 subgroups x 32 lanes. Software-pipelined: next 8-edge
// metadata batch is loaded BEFORE the current batch's gathers -> ~16
// outstanding loads/wave. launch_bounds(256,4): VGPR cap 128 (needs ~60).
// ---------------------------------------------------------------------------
__global__ __launch_bounds__(256, 4) void apply1_k(const uint2* __restrict__ edata,
                                                   const int* __restrict__ bktstart,
                                                   const float* __restrict__ XW1,
                                                   const float* __restrict__ W2,
                                                   float* __restrict__ HW2) {
    constexpr int NSUB = 8, U = 8, STEP = NSUB * U;   // 64 edges per iter
    __shared__ float acc[64 * 33];
    int t = threadIdx.x, b = blockIdx.x;
    for (int i = t; i < 64 * 33; i += 256) acc[i] = 0.f;
    __syncthreads();
    int base = bktstart[b], end = bktstart[b + 1];
    int sub = t >> 5, j = t & 31;
    int i = base + sub;
    uint2 ecur[U];
    bool have = (i + (U - 1) * NSUB < end);
    if (have) {
#pragma unroll
        for (int u = 0; u < U; ++u) ecur[u] = edata[i + u * NSUB];
    }
    while (have) {
        int inext = i + STEP;
        bool havenext = (inext + (U - 1) * NSUB < end);
        uint2 enxt[U];
        if (havenext) {
#pragma unroll
            for (int u = 0; u < U; ++u) enxt[u] = edata[inext + u * NSUB];
        }
        float x[U];
#pragma unroll
        for (int u = 0; u < U; ++u) x[u] = XW1[(size_t)(ecur[u].x >> 6) * C1 + j];
#pragma unroll
        for (int u = 0; u < U; ++u)
            atomicAdd(&acc[(ecur[u].x & 63u) * 33 + j], __uint_as_float(ecur[u].y) * x[u]);
#pragma unroll
        for (int u = 0; u < U; ++u) ecur[u] = enxt[u];
        i = inext;
        have = havenext;
    }
    for (; i < end; i += NSUB) {
        uint2 ed = edata[i];
        float x = XW1[(size_t)(ed.x >> 6) * C1 + j];
        atomicAdd(&acc[(ed.x & 63u) * 33 + j], __uint_as_float(ed.y) * x);
    }
    __syncthreads();
    // epilogue: relu + @W2. thread t: row r = t>>2, output quad s = t&3
    int r = t >> 2, s = t & 3;
    int grow = b * 64 + r;
    if (grow < NN) {
        float o0 = 0.f, o1 = 0.f, o2 = 0.f, o3 = 0.f;
#pragma unroll
        for (int k = 0; k < C1; ++k) {
            float h = fmaxf(acc[r * 33 + k], 0.f);
            const float* w = W2 + k * C2 + 4 * s;
            o0 = fmaf(h, w[0], o0);
            o1 = fmaf(h, w[1], o1);
            o2 = fmaf(h, w[2], o2);
            o3 = fmaf(h, w[3], o3);
        }
        *reinterpret_cast<float4*>(HW2 + (size_t)grow * C2 + 4 * s) =
            make_float4(o0, o1, o2, o3);
    }
}

// ---------------------------------------------------------------------------
// apply2: out = Lap @ HW2 in LDS, fused row-L2 norm. 256 threads = 16
// subgroups x 16 lanes, same prefetch pipeline.
// ---------------------------------------------------------------------------
__global__ __launch_bounds__(256, 4) void apply2_k(const uint2* __restrict__ edata,
                                                   const int* __restrict__ bktstart,
                                                   const float* __restrict__ HW2,
                                                   float* __restrict__ out) {
    constexpr int NSUB = 16, U = 8, STEP = NSUB * U;   // 128 edges per iter
    __shared__ float acc[64 * 17];
    int t = threadIdx.x, b = blockIdx.x;
    for (int i = t; i < 64 * 17; i += 256) acc[i] = 0.f;
    __syncthreads();
    int base = bktstart[b], end = bktstart[b + 1];
    int sub = t >> 4, j = t & 15;
    int i = base + sub;
    uint2 ecur[U];
    bool have = (i + (U - 1) * NSUB < end);
    if (have) {
#pragma unroll
        for (int u = 0; u < U; ++u) ecur[u] = edata[i + u * NSUB];
    }
    while (have) {
        int inext = i + STEP;
        bool havenext = (inext + (U - 1) * NSUB < end);
        uint2 enxt[U];
        if (havenext) {
#pragma unroll
            for (int u = 0; u < U; ++u) enxt[u] = edata[inext + u * NSUB];
        }
        float x[U];
#pragma unroll
        for (int u = 0; u < U; ++u) x[u] = HW2[(size_t)(ecur[u].x >> 6) * C2 + j];
#pragma unroll
        for (int u = 0; u < U; ++u)
            atomicAdd(&acc[(ecur[u].x & 63u) * 17 + j], __uint_as_float(ecur[u].y) * x[u]);
#pragma unroll
        for (int u = 0; u < U; ++u) ecur[u] = enxt[u];
        i = inext;
        have = havenext;
    }
    for (; i < end; i += NSUB) {
        uint2 ed = edata[i];
        float x = HW2[(size_t)(ed.x >> 6) * C2 + j];
        atomicAdd(&acc[(ed.x & 63u) * 17 + j], __uint_as_float(ed.y) * x);
    }
    __syncthreads();
    // epilogue: row-L2 norm; 16 consecutive lanes per row -> coalesced writes
    for (int r = (t >> 4); r < 64; r += 16) {
        int grow = b * 64 + r;
        if (grow >= NN) break;
        float val = acc[r * 17 + j];
        float s = val * val;
#pragma unroll
        for (int m = 1; m < 16; m <<= 1) s += __shfl_xor(s, m);
        out[(size_t)grow * C2 + j] = val / fmaxf(sqrtf(s), EPS_NORM);
    }
}

// ---------------------------------------------------------------------------
// Fallback path (atomic scatter, round-4 style) if ws_size is too small.
// ---------------------------------------------------------------------------
__global__ __launch_bounds__(64) void gemm2_k(const float* __restrict__ H1,
                                              const float* __restrict__ W2,
                                              float* __restrict__ HW2) {
    int row = blockIdx.x * 64 + threadIdx.x;
    if (row >= NN) return;
    float h[C1];
    const float4* hr = reinterpret_cast<const float4*>(H1 + (size_t)row * C1);
#pragma unroll
    for (int q = 0; q < C1 / 4; ++q) {
        float4 v = hr[q];
        h[4 * q + 0] = fmaxf(v.x, 0.f);
        h[4 * q + 1] = fmaxf(v.y, 0.f);
        h[4 * q + 2] = fmaxf(v.z, 0.f);
        h[4 * q + 3] = fmaxf(v.w, 0.f);
    }
    float acc[C2];
#pragma unroll
    for (int j = 0; j < C2; ++j) acc[j] = 0.f;
#pragma unroll
    for (int k = 0; k < C1; ++k) {
        const float* w = W2 + k * C2;
#pragma unroll
        for (int j = 0; j < C2; ++j) acc[j] = fmaf(h[k], w[j], acc[j]);
    }
    float4* o = reinterpret_cast<float4*>(HW2 + (size_t)row * C2);
#pragma unroll
    for (int q = 0; q < C2 / 4; ++q)
        o[q] = make_float4(acc[4 * q], acc[4 * q + 1], acc[4 * q + 2], acc[4 * q + 3]);
}

template <int F>
__global__ __launch_bounds__(256) void spmm_k(const int* __restrict__ rows,
                                              const int* __restrict__ cols,
                                              const float* __restrict__ vals,
                                              const float* __restrict__ Hin,
                                              float* __restrict__ Hout) {
    constexpr int SH = (F == 32) ? 5 : 4;
    constexpr int MSK = F - 1;
    long long total = (long long)NE << SH;
    long long stride = (long long)gridDim.x * 256;
    for (long long idx = (long long)blockIdx.x * 256 + threadIdx.x; idx < total;
         idx += stride) {
        int e = (int)(idx >> SH);
        int j = (int)(idx & MSK);
        float contrib = vals[e] * Hin[(size_t)cols[e] * F + j];
        unsafeAtomicAdd(&Hout[(size_t)rows[e] * F + j], contrib);
    }
}

__global__ __launch_bounds__(256) void norm_k(float* __restrict__ H) {
    int t = blockIdx.x * 256 + threadIdx.x;
    if (t >= NN * C2) return;
    float v = H[t];
    float s = v * v;
#pragma unroll
    for (int m = 1; m < C2; m <<= 1) s += __shfl_xor(s, m, C2);
    H[t] = v / fmaxf(sqrtf(s), EPS_NORM);
}

extern "C" void kernel_launch(void* const* d_in, const int* in_sizes, int n_in,
                              void* d_out, int out_size, void* d_ws, size_t ws_size,
                              hipStream_t stream) {
    const float* X = (const float*)d_in[0];
    const float* W1 = (const float*)d_in[1];
    const float* W2 = (const float*)d_in[2];
    const int* lap_rows = (const int*)d_in[3];
    const int* lap_cols = (const int*)d_in[4];
    const float* vals = (const float*)d_in[5];
    float* out = (float*)d_out;

    // workspace layout (main path): ~46.5 MB
    float* XW1 = (float*)d_ws;                            // NN*C1
    float* HW2 = XW1 + (size_t)NN * C1;                   // NN*C2
    uint2* edata = (uint2*)(HW2 + (size_t)NN * C2);       // NE uint2
    int* blkcnt = (int*)(edata + NE);                     // NBKT*NCH
    int* bkttot = blkcnt + (size_t)NBKT * NCH;            // NBKT
    int* bktstart = bkttot + NBKT;                        // NBKT+1
    size_t need = (size_t)((char*)(bktstart + NBKT + 1) - (char*)d_ws);

    if (ws_size >= need) {
        bh_k<<<NCH, 512, 0, stream>>>(lap_rows, blkcnt);
        bscan_k<<<NBKT, NCH, 0, stream>>>(blkcnt, bkttot);
        bscan2_k<<<1, 1024, 0, stream>>>(bkttot, bktstart);
        bfill_k<<<NCH, 512, 0, stream>>>(lap_rows, lap_cols, vals, blkcnt,
                                         bktstart, edata);
        gemm1_k<<<NBKT, 256, 0, stream>>>(X, W1, XW1);
        apply1_k<<<NBKT, 256, 0, stream>>>(edata, bktstart, XW1, W2, HW2);
        apply2_k<<<NBKT, 256, 0, stream>>>(edata, bktstart, HW2, out);
    } else {
        // fallback: atomic-scatter path (32 MB of ws)
        float* H1 = (float*)edata;   // reuse region
        hipMemsetAsync(H1, 0, (size_t)NN * C1 * sizeof(float), stream);
        hipMemsetAsync(out, 0, (size_t)NN * C2 * sizeof(float), stream);
        gemm1_k<<<NBKT, 256, 0, stream>>>(X, W1, XW1);
        spmm_k<C1><<<16384, 256, 0, stream>>>(lap_rows, lap_cols, vals, XW1, H1);
        gemm2_k<<<(NN + 63) / 64, 64, 0, stream>>>(H1, W2, HW2);
        spmm_k<C2><<<8192, 256, 0, stream>>>(lap_rows, lap_cols, vals, HW2, out);
        norm_k<<<((NN * C2) + 255) / 256, 256, 0, stream>>>(out);
    }
}

// Round 15
// 1274.917 us; speedup vs baseline: 1.2408x; 1.0655x over previous
//
#include <hip/hip_runtime.h>
#include <math.h>

// Problem constants (match reference)
constexpr int NN = 100000;     // nodes
constexpr int DF = 512;        // input features
constexpr int C1 = 32;         // layer-1 width
constexpr int C2 = 16;         // layer-2 width
constexpr int NE = 3200000;    // edges
#define EPS_NORM 1e-7f

constexpr int BKT = 64;                      // rows per bucket
constexpr int NBKT = (NN + BKT - 1) / BKT;   // 1563
constexpr int NCH = 256;                     // binning chunks
constexpr int CHUNK = NE / NCH;              // 12500 (exact)
constexpr int SPLIT = 4;                     // blocks per bucket (TLP lever)

// ---------------------------------------------------------------------------
// gemm1: XW1 = X @ W1. Block = 4 waves x 64 rows; wave wc streams K-quarter.
// ---------------------------------------------------------------------------
__global__ __launch_bounds__(256, 4) void gemm1_k(const float* __restrict__ X,
                                                  const float* __restrict__ W1,
                                                  float* __restrict__ XW1) {
    __shared__ float part[64][36];
    int t = threadIdx.x;
    int l = t & 63;
    int wc = __builtin_amdgcn_readfirstlane(t >> 6);
    int grow = blockIdx.x * 64 + l;
    bool valid = grow < NN;
    float acc[C1];
#pragma unroll
    for (int j = 0; j < C1; ++j) acc[j] = 0.f;
    if (valid) {
        const float4* xp = reinterpret_cast<const float4*>(X + (size_t)grow * DF + wc * 128);
        const float* wb = W1 + (size_t)wc * 128 * C1;
#pragma unroll 1
        for (int kk = 0; kk < 32; kk += 8) {
            float4 xv[8];
#pragma unroll
            for (int u = 0; u < 8; ++u) xv[u] = xp[kk + u];
#pragma unroll
            for (int u = 0; u < 8; ++u) {
                const float* w = wb + (size_t)(kk + u) * 4 * C1;   // wave-uniform
#pragma unroll
                for (int j = 0; j < C1; ++j) acc[j] = fmaf(xv[u].x, w[j], acc[j]);
#pragma unroll
                for (int j = 0; j < C1; ++j) acc[j] = fmaf(xv[u].y, w[C1 + j], acc[j]);
#pragma unroll
                for (int j = 0; j < C1; ++j) acc[j] = fmaf(xv[u].z, w[2 * C1 + j], acc[j]);
#pragma unroll
                for (int j = 0; j < C1; ++j) acc[j] = fmaf(xv[u].w, w[3 * C1 + j], acc[j]);
            }
        }
    }
    if (wc == 0) {
#pragma unroll
        for (int j = 0; j < C1; ++j) part[l][j] = acc[j];
    }
    __syncthreads();
    if (wc == 1) {
#pragma unroll
        for (int j = 0; j < C1; ++j) part[l][j] += acc[j];
    }
    __syncthreads();
    if (wc == 2) {
#pragma unroll
        for (int j = 0; j < C1; ++j) part[l][j] += acc[j];
    }
    __syncthreads();
    if (wc == 3 && valid) {
        float4* o = reinterpret_cast<float4*>(XW1 + (size_t)grow * C1);
#pragma unroll
        for (int q = 0; q < C1 / 4; ++q) {
            float4 r;
            r.x = part[l][4 * q + 0] + acc[4 * q + 0];
            r.y = part[l][4 * q + 1] + acc[4 * q + 1];
            r.z = part[l][4 * q + 2] + acc[4 * q + 2];
            r.w = part[l][4 * q + 3] + acc[4 * q + 3];
            o[q] = r;
        }
    }
}

// ---------------------------------------------------------------------------
// Binning: edges -> 1563 buckets of 64 rows (histogram, scans, fill).
// Payload: edata = { (col<<6)|rowlocal , bits(val) }.
// ---------------------------------------------------------------------------
__global__ __launch_bounds__(512) void bh_k(const int* __restrict__ rows,
                                            int* __restrict__ blkcnt) {
    __shared__ int lh[NBKT];
    int t = threadIdx.x, bi = blockIdx.x;
    for (int i = t; i < NBKT; i += 512) lh[i] = 0;
    __syncthreads();
    int base = bi * CHUNK;
    for (int i = t; i < CHUNK; i += 512)
        atomicAdd(&lh[rows[base + i] >> 6], 1);
    __syncthreads();
    for (int i = t; i < NBKT; i += 512) blkcnt[(size_t)i * NCH + bi] = lh[i];
}

__global__ __launch_bounds__(NCH) void bscan_k(int* __restrict__ blkcnt,
                                               int* __restrict__ bkttot) {
    __shared__ int sh[NCH];
    int t = threadIdx.x, b = blockIdx.x;
    int v = blkcnt[(size_t)b * NCH + t];
    sh[t] = v;
    __syncthreads();
#pragma unroll
    for (int off = 1; off < NCH; off <<= 1) {
        int u = (t >= off) ? sh[t - off] : 0;
        __syncthreads();
        sh[t] += u;
        __syncthreads();
    }
    blkcnt[(size_t)b * NCH + t] = sh[t] - v;   // exclusive
    if (t == NCH - 1) bkttot[b] = sh[t];
}

__global__ __launch_bounds__(1024) void bscan2_k(const int* __restrict__ bkttot,
                                                 int* __restrict__ bktstart) {
    __shared__ int sh[1024];
    int t = threadIdx.x;
    int i0 = 2 * t, i1 = 2 * t + 1;
    int a = (i0 < NBKT) ? bkttot[i0] : 0;
    int b = (i1 < NBKT) ? bkttot[i1] : 0;
    int s = a + b;
    sh[t] = s;
    __syncthreads();
#pragma unroll
    for (int off = 1; off < 1024; off <<= 1) {
        int u = (t >= off) ? sh[t - off] : 0;
        __syncthreads();
        sh[t] += u;
        __syncthreads();
    }
    int excl = sh[t] - s;
    if (i0 < NBKT) bktstart[i0] = excl;
    if (i1 < NBKT) bktstart[i1] = excl + a;
    if (t == 0) bktstart[NBKT] = NE;
}

__global__ __launch_bounds__(512) void bfill_k(const int* __restrict__ rows,
                                               const int* __restrict__ cols,
                                               const float* __restrict__ vals,
                                               const int* __restrict__ blkcnt,
                                               const int* __restrict__ bktstart,
                                               uint2* __restrict__ edata) {
    __shared__ int cur[NBKT];
    int t = threadIdx.x, bi = blockIdx.x;
    for (int i = t; i < NBKT; i += 512) cur[i] = 0;
    __syncthreads();
    int base = bi * CHUNK;
    for (int i = t; i < CHUNK; i += 512) {
        int e = base + i;
        int r = rows[e];
        int bkt = r >> 6;
        int rank = atomicAdd(&cur[bkt], 1);
        int dst = bktstart[bkt] + blkcnt[(size_t)bkt * NCH + bi] + rank;
        edata[dst] = make_uint2(((unsigned)cols[e] << 6) | (unsigned)(r & 63),
                                __float_as_uint(vals[e]));
    }
}

// ---------------------------------------------------------------------------
// apply1split: H1 += partial(Lap @ XW1). Grid = NBKT*SPLIT blocks (6252) ->
// ~24 blocks/CU demand -> full 32-wave occupancy, r4-style TLP (the only
// lever that has moved this gather workload). Per-block LDS partial tile,
// flushed with coalesced unsafeAtomicAdd (51 MB total, line-packed).
// ---------------------------------------------------------------------------
__global__ __launch_bounds__(256) void apply1_k(const uint2* __restrict__ edata,
                                                const int* __restrict__ bktstart,
                                                const float* __restrict__ XW1,
                                                float* __restrict__ H1) {
    constexpr int NSUB = 8, U = 4;
    __shared__ float acc[64 * 33];
    int t = threadIdx.x;
    int b = blockIdx.x / SPLIT, s = blockIdx.x % SPLIT;
    for (int i = t; i < 64 * 33; i += 256) acc[i] = 0.f;
    __syncthreads();
    int bs = bktstart[b], len = bktstart[b + 1] - bs;
    int start = bs + (int)(((long long)len * s) / SPLIT);
    int end = bs + (int)(((long long)len * (s + 1)) / SPLIT);
    int sub = t >> 5, j = t & 31;
    int i = start + sub;
    for (; i + (U - 1) * NSUB < end; i += U * NSUB) {
        uint2 ed[U];
#pragma unroll
        for (int u = 0; u < U; ++u) ed[u] = edata[i + u * NSUB];
        float x[U];
#pragma unroll
        for (int u = 0; u < U; ++u) x[u] = XW1[(size_t)(ed[u].x >> 6) * C1 + j];
#pragma unroll
        for (int u = 0; u < U; ++u)
            atomicAdd(&acc[(ed[u].x & 63u) * 33 + j], __uint_as_float(ed[u].y) * x[u]);
    }
    for (; i < end; i += NSUB) {
        uint2 ed = edata[i];
        float x = XW1[(size_t)(ed.x >> 6) * C1 + j];
        atomicAdd(&acc[(ed.x & 63u) * 33 + j], __uint_as_float(ed.y) * x);
    }
    __syncthreads();
    // flush: coalesced global atomics (lanes 0..31 -> one 128B line)
    for (int idx = t; idx < 64 * C1; idx += 256) {
        int r = idx >> 5, jj = idx & 31;
        int grow = b * 64 + r;
        if (grow < NN) {
            float v = acc[r * 33 + jj];
            unsafeAtomicAdd(&H1[(size_t)grow * C1 + jj], v);
        }
    }
}

// ---------------------------------------------------------------------------
// apply2split: out += partial(Lap @ HW2). Same structure, 16-lane subgroups.
// ---------------------------------------------------------------------------
__global__ __launch_bounds__(256) void apply2_k(const uint2* __restrict__ edata,
                                                const int* __restrict__ bktstart,
                                                const float* __restrict__ HW2,
                                                float* __restrict__ out) {
    constexpr int NSUB = 16, U = 4;
    __shared__ float acc[64 * 17];
    int t = threadIdx.x;
    int b = blockIdx.x / SPLIT, s = blockIdx.x % SPLIT;
    for (int i = t; i < 64 * 17; i += 256) acc[i] = 0.f;
    __syncthreads();
    int bs = bktstart[b], len = bktstart[b + 1] - bs;
    int start = bs + (int)(((long long)len * s) / SPLIT);
    int end = bs + (int)(((long long)len * (s + 1)) / SPLIT);
    int sub = t >> 4, j = t & 15;
    int i = start + sub;
    for (; i + (U - 1) * NSUB < end; i += U * NSUB) {
        uint2 ed[U];
#pragma unroll
        for (int u = 0; u < U; ++u) ed[u] = edata[i + u * NSUB];
        float x[U];
#pragma unroll
        for (int u = 0; u < U; ++u) x[u] = HW2[(size_t)(ed[u].x >> 6) * C2 + j];
#pragma unroll
        for (int u = 0; u < U; ++u)
            atomicAdd(&acc[(ed[u].x & 63u) * 17 + j], __uint_as_float(ed[u].y) * x[u]);
    }
    for (; i < end; i += NSUB) {
        uint2 ed = edata[i];
        float x = HW2[(size_t)(ed.x >> 6) * C2 + j];
        atomicAdd(&acc[(ed.x & 63u) * 17 + j], __uint_as_float(ed.y) * x);
    }
    __syncthreads();
    // flush: lanes 0..15 -> one 64B line per row
    for (int idx = t; idx < 64 * C2; idx += 256) {
        int r = idx >> 4, jj = idx & 15;
        int grow = b * 64 + r;
        if (grow < NN) {
            float v = acc[r * 17 + jj];
            unsafeAtomicAdd(&out[(size_t)grow * C2 + jj], v);
        }
    }
}

// ---------------------------------------------------------------------------
// gemm2: HW2[row] = relu(H1[row]) @ W2   (one thread per row)
// ---------------------------------------------------------------------------
__global__ __launch_bounds__(256) void gemm2_k(const float* __restrict__ H1,
                                               const float* __restrict__ W2,
                                               float* __restrict__ HW2) {
    int row = blockIdx.x * 256 + threadIdx.x;
    if (row >= NN) return;
    float h[C1];
    const float4* hr = reinterpret_cast<const float4*>(H1 + (size_t)row * C1);
#pragma unroll
    for (int q = 0; q < C1 / 4; ++q) {
        float4 v = hr[q];
        h[4 * q + 0] = fmaxf(v.x, 0.f);
        h[4 * q + 1] = fmaxf(v.y, 0.f);
        h[4 * q + 2] = fmaxf(v.z, 0.f);
        h[4 * q + 3] = fmaxf(v.w, 0.f);
    }
    float acc[C2];
#pragma unroll
    for (int j = 0; j < C2; ++j) acc[j] = 0.f;
#pragma unroll
    for (int k = 0; k < C1; ++k) {
        const float* w = W2 + k * C2;   // uniform
#pragma unroll
        for (int j = 0; j < C2; ++j) acc[j] = fmaf(h[k], w[j], acc[j]);
    }
    float4* o = reinterpret_cast<float4*>(HW2 + (size_t)row * C2);
#pragma unroll
    for (int q = 0; q < C2 / 4; ++q)
        o[q] = make_float4(acc[4 * q], acc[4 * q + 1], acc[4 * q + 2], acc[4 * q + 3]);
}

// normalize rows of out (N x 16) in place
__global__ __launch_bounds__(256) void norm_k(float* __restrict__ H) {
    int t = blockIdx.x * 256 + threadIdx.x;
    if (t >= NN * C2) return;
    float v = H[t];
    float s = v * v;
#pragma unroll
    for (int m = 1; m < C2; m <<= 1) s += __shfl_xor(s, m, C2);
    H[t] = v / fmaxf(sqrtf(s), EPS_NORM);
}

// ---------------------------------------------------------------------------
// Fallback path (atomic scatter, round-4 style) if ws_size is too small.
// ---------------------------------------------------------------------------
template <int F>
__global__ __launch_bounds__(256) void spmm_k(const int* __restrict__ rows,
                                              const int* __restrict__ cols,
                                              const float* __restrict__ vals,
                                              const float* __restrict__ Hin,
                                              float* __restrict__ Hout) {
    constexpr int SH = (F == 32) ? 5 : 4;
    constexpr int MSK = F - 1;
    long long total = (long long)NE << SH;
    long long stride = (long long)gridDim.x * 256;
    for (long long idx = (long long)blockIdx.x * 256 + threadIdx.x; idx < total;
         idx += stride) {
        int e = (int)(idx >> SH);
        int j = (int)(idx & MSK);
        float contrib = vals[e] * Hin[(size_t)cols[e] * F + j];
        unsafeAtomicAdd(&Hout[(size_t)rows[e] * F + j], contrib);
    }
}

extern "C" void kernel_launch(void* const* d_in, const int* in_sizes, int n_in,
                              void* d_out, int out_size, void* d_ws, size_t ws_size,
                              hipStream_t stream) {
    const float* X = (const float*)d_in[0];
    const float* W1 = (const float*)d_in[1];
    const float* W2 = (const float*)d_in[2];
    const int* lap_rows = (const int*)d_in[3];
    const int* lap_cols = (const int*)d_in[4];
    const float* vals = (const float*)d_in[5];
    float* out = (float*)d_out;

    // workspace layout (main path): ~52.8 MB.  HW2 aliases XW1 (XW1 dead
    // after apply1split; gemm2 reads H1, writes the alias).
    float* XW1 = (float*)d_ws;                            // NN*C1
    float* H1 = XW1 + (size_t)NN * C1;                    // NN*C1
    uint2* edata = (uint2*)(H1 + (size_t)NN * C1);        // NE uint2
    int* blkcnt = (int*)(edata + NE);                     // NBKT*NCH
    int* bkttot = blkcnt + (size_t)NBKT * NCH;            // NBKT
    int* bktstart = bkttot + NBKT;                        // NBKT+1
    float* HW2 = XW1;                                     // alias
    size_t need = (size_t)((char*)(bktstart + NBKT + 1) - (char*)d_ws);

    if (ws_size >= need) {
        // binning
        bh_k<<<NCH, 512, 0, stream>>>(lap_rows, blkcnt);
        bscan_k<<<NBKT, NCH, 0, stream>>>(blkcnt, bkttot);
        bscan2_k<<<1, 1024, 0, stream>>>(bkttot, bktstart);
        bfill_k<<<NCH, 512, 0, stream>>>(lap_rows, lap_cols, vals, blkcnt,
                                         bktstart, edata);
        // pipeline
        gemm1_k<<<NBKT, 256, 0, stream>>>(X, W1, XW1);
        hipMemsetAsync(H1, 0, (size_t)NN * C1 * sizeof(float), stream);
        apply1_k<<<NBKT * SPLIT, 256, 0, stream>>>(edata, bktstart, XW1, H1);
        gemm2_k<<<(NN + 255) / 256, 256, 0, stream>>>(H1, W2, HW2);
        hipMemsetAsync(out, 0, (size_t)NN * C2 * sizeof(float), stream);
        apply2_k<<<NBKT * SPLIT, 256, 0, stream>>>(edata, bktstart, HW2, out);
        norm_k<<<((NN * C2) + 255) / 256, 256, 0, stream>>>(out);
    } else {
        // fallback: atomic-scatter path (32 MB of ws)
        float* H1f = (float*)edata;   // reuse region
        hipMemsetAsync(H1f, 0, (size_t)NN * C1 * sizeof(float), stream);
        hipMemsetAsync(out, 0, (size_t)NN * C2 * sizeof(float), stream);
        gemm1_k<<<NBKT, 256, 0, stream>>>(X, W1, XW1);
        spmm_k<C1><<<16384, 256, 0, stream>>>(lap_rows, lap_cols, vals, XW1, H1f);
        gemm2_k<<<(NN + 255) / 256, 256, 0, stream>>>(H1f, W2, XW1);
        spmm_k<C2><<<8192, 256, 0, stream>>>(lap_rows, lap_cols, vals, XW1, out);
        norm_k<<<((NN * C2) + 255) / 256, 256, 0, stream>>>(out);
    }
}